// Round 3
// baseline (368.708 us; speedup 1.0000x reference)
//
#include <hip/hip_runtime.h>
#include <math.h>

#define DD 16
#define HH 64
#define WW 64
#define VV (DD*HH*WW)      // 65536
#define CC 64
#define NHEADS 4
#define NSAMP 8
#define HDIM 16

typedef unsigned int uint;
typedef unsigned short ushort;
typedef __attribute__((ext_vector_type(8))) short bf16x8;
typedef __attribute__((ext_vector_type(4))) float f32x4;

__device__ __forceinline__ float clampf(float v, float lo, float hi){ return fminf(fmaxf(v, lo), hi); }
__device__ __forceinline__ int imin(int a, int b){ return a < b ? a : b; }

// bf16 helpers (RNE)
__device__ __forceinline__ ushort f2bf(float f){
  uint u = __float_as_uint(f);
  uint r = (u + 0x7fffu + ((u>>16)&1u)) >> 16;
  return (ushort)r;
}
__device__ __forceinline__ uint packbf2(float a, float b){
  return (uint)f2bf(a) | ((uint)f2bf(b) << 16);
}
__device__ __forceinline__ float bflo(uint u){ return __uint_as_float(u << 16); }
__device__ __forceinline__ float bfhi(uint u){ return __uint_as_float(u & 0xffff0000u); }
__device__ __forceinline__ float bf2f(ushort u){ return __uint_as_float((uint)u << 16); }

__device__ __forceinline__ float fast_tanh(float x){
  float e = __expf(2.f*x);
  return 1.f - 2.f/(e + 1.f);
}

// ---- input pack: occ/prev fp32 -> bf16 pair planes [call][32cp][VV] ------
__global__ __launch_bounds__(256) void pack_in(const float* __restrict__ a,
                                               const float* __restrict__ b,
                                               uint* __restrict__ o){
  int idx = blockIdx.x*256 + threadIdx.x;   // 2*32*VV/4 = 1,048,576
  int v4 = (idx & (VV/4 - 1)) * 4;
  int rest = idx >> 14;
  int cp = rest & 31;
  int call = rest >> 5;
  const float* x = call ? b : a;
  float4 f0 = *reinterpret_cast<const float4*>(x + (size_t)(2*cp)*VV + v4);
  float4 f1 = *reinterpret_cast<const float4*>(x + (size_t)(2*cp+1)*VV + v4);
  uint4 pk;
  pk.x = packbf2(f0.x, f1.x);
  pk.y = packbf2(f0.y, f1.y);
  pk.z = packbf2(f0.z, f1.z);
  pk.w = packbf2(f0.w, f1.w);
  *reinterpret_cast<uint4*>(o + (size_t)(call*32+cp)*VV + v4) = pk;
}

// ---- zpair transform: vols [h][y][x][z][16dw(ch-pairs)] ->
//      vols2 [h][y][x][z][32dw] where dword c = (ch c @ z, ch c @ z+1) -----
__global__ __launch_bounds__(256) void zpair(const uint* __restrict__ vin,
                                             uint* __restrict__ vout){
  int idx = blockIdx.x*256 + threadIdx.x;   // 4*VV*16 = 4,194,304
  int j = idx & 15;
  int rest = idx >> 4;                      // (head,(y,x),z), z fastest
  int z = rest & 15;
  uint uz  = vin[idx];
  uint uz1 = vin[(z < 15) ? idx + 16 : idx];
  uint lo = __builtin_amdgcn_perm(uz1, uz, 0x05040100u);  // (ch2j@z, ch2j@z+1)
  uint hi = __builtin_amdgcn_perm(uz1, uz, 0x07060302u);  // (ch2j+1@z, ch2j+1@z+1)
  uint2 pk; pk.x = lo; pk.y = hi;
  *reinterpret_cast<uint2*>(vout + ((size_t)rest << 5) + 2*j) = pk;
}

// ---- weight repacks ------------------------------------------------------
__global__ void repack_wmfma(const float* __restrict__ w, uint* __restrict__ o, int MG){
  int U = blockIdx.x*256 + threadIdx.x;
  int total = 54*MG*256;
  if (U >= total) return;
  int j2 = U & 3;
  int m  = (U>>2) & 15;
  int q  = (U>>6) & 3;
  int rest = U >> 8;          // s*MG + g
  int g = rest % MG;
  int s = rest / MG;
  int tap = s >> 1, h = s & 1;
  int co = g*16 + m;
  int ci = h*32 + q*8 + j2*2;
  int base = co*1728 + ci*27 + tap;
  o[U] = packbf2(w[base], w[base + 27]);
}
__global__ void repack_w1mfma(const float* __restrict__ w, uint* __restrict__ o, int MT){
  int U = blockIdx.x*256 + threadIdx.x;
  int total = 2*MT*256;
  if (U >= total) return;
  int j2 = U & 3;
  int lane = (U>>2) & 63;
  int frag = U >> 8;
  int mt = frag % MT;
  int ks = frag / MT;
  int q = lane >> 4, m = lane & 15;
  int co = mt*16 + m;
  int ci = ks*32 + q*8 + j2*2;
  o[U] = packbf2(w[co*CC + ci], w[co*CC + ci + 1]);
}

// ---- 1x1 conv via MFMA ---------------------------------------------------
// EPI 0: fp32 input (mid); +bias, pack bf16 -> vols[head][y][x][z][32ch]
// EPI 1: packed input (o0pk); (acc+bias)*0.25 -> bf16 q [call][vox][64ch]
template<int CO, int EPI>
__global__ __launch_bounds__(256) void conv1_mfma(
    const void* __restrict__ xa, const void* __restrict__ xb,
    const uint* __restrict__ wA, const float* __restrict__ bias,
    void* __restrict__ outp)
{
  constexpr int MT = CO/16;
  constexpr int MW = MT/4;
  __shared__ ushort xt[64*72];    // 9216 B
  int tid = threadIdx.x;
  int lane = tid & 63;
  int g = __builtin_amdgcn_readfirstlane(tid >> 6);
  int q = lane >> 4, n = lane & 15;
  int call = blockIdx.x >> 10;
  int v0 = (blockIdx.x & 1023) * 64;
  if constexpr (EPI == 0){
    const float* x = call ? (const float*)xb : (const float*)xa;
    for (int it = tid; it < 64*32; it += 256){
      int vox = it & 63; int cp = it >> 6;
      float a = x[(size_t)(2*cp)*VV + v0 + vox];
      float b = x[(size_t)(2*cp+1)*VV + v0 + vox];
      *reinterpret_cast<uint*>(&xt[vox*72 + 2*cp]) = packbf2(a,b);
    }
  } else {
    const uint* xp = (const uint*)xa + (size_t)call*32*VV;
    for (int it = tid; it < 64*32; it += 256){
      int vox = it & 63; int cp = it >> 6;
      *reinterpret_cast<uint*>(&xt[vox*72 + 2*cp]) = xp[(size_t)cp*VV + v0 + vox];
    }
  }
  __syncthreads();
  f32x4 acc[MW][4];
  #pragma unroll
  for (int mw=0;mw<MW;mw++)
    #pragma unroll
    for (int nt=0;nt<4;nt++){ acc[mw][nt].x=0.f; acc[mw][nt].y=0.f; acc[mw][nt].z=0.f; acc[mw][nt].w=0.f; }
  const char* ldsb = reinterpret_cast<const char*>(xt);
  const char* wac  = reinterpret_cast<const char*>(wA);
  #pragma unroll
  for (int ks=0; ks<2; ks++){
    bf16x8 bfr[4];
    #pragma unroll
    for (int nt=0; nt<4; nt++)
      bfr[nt] = *reinterpret_cast<const bf16x8*>(ldsb + ((nt*16+n)*144 + q*16 + ks*64));
    #pragma unroll
    for (int mw=0; mw<MW; mw++){
      int mt = g*MW + mw;
      bf16x8 af = *reinterpret_cast<const bf16x8*>(wac + (size_t)((ks*MT + mt)*64 + lane)*16);
      #pragma unroll
      for (int nt=0; nt<4; nt++)
        acc[mw][nt] = __builtin_amdgcn_mfma_f32_16x16x32_bf16(af, bfr[nt], acc[mw][nt], 0, 0, 0);
    }
  }
  if constexpr (EPI == 0){
    #pragma unroll
    for (int mw=0; mw<MW; mw++){
      int mt = g*MW + mw;
      int cob = mt*16 + q*4;
      #pragma unroll
      for (int nt=0; nt<4; nt++){
        int v = v0 + nt*16 + n;
        float r0 = acc[mw][nt].x + bias[cob+0];
        float r1 = acc[mw][nt].y + bias[cob+1];
        float r2 = acc[mw][nt].z + bias[cob+2];
        float r3 = acc[mw][nt].w + bias[cob+3];
        int z = v >> 12, y = (v >> 6) & 63, xx = v & 63;
        int head = cob >> 5;
        uint* vols = (uint*)outp;
        uint2 pk; pk.x = packbf2(r0,r1); pk.y = packbf2(r2,r3);
        *reinterpret_cast<uint2*>(vols + ((size_t)head*VV + (size_t)(y*WW+xx)*DD + z)*16 + ((cob&31)>>1)) = pk;
      }
    }
  } else {
    // re-tile through LDS -> coalesced 8KB linear store
    __syncthreads();
    ushort* xr = xt;            // reuse as [vox64][64ch]
    int cob = g*16 + q*4;       // MW==1
    #pragma unroll
    for (int nt=0; nt<4; nt++){
      int vox = nt*16 + n;
      uint2 pk;
      pk.x = packbf2((acc[0][nt].x + bias[cob+0])*0.25f, (acc[0][nt].y + bias[cob+1])*0.25f);
      pk.y = packbf2((acc[0][nt].z + bias[cob+2])*0.25f, (acc[0][nt].w + bias[cob+3])*0.25f);
      *reinterpret_cast<uint2*>(&xr[vox*64 + cob]) = pk;
    }
    __syncthreads();
    char* ob = (char*)((ushort*)outp + (size_t)call*CC*VV) + (size_t)v0*128;
    const char* lb = reinterpret_cast<const char*>(xr);
    #pragma unroll
    for (int k=0; k<2; k++){
      int idx = tid + k*256;    // 512 x uint4 = 8KB
      *reinterpret_cast<uint4*>(ob + idx*16) = *reinterpret_cast<const uint4*>(lb + idx*16);
    }
  }
}

// ---- 3x3x3 conv via implicit-GEMM MFMA, batched over 2 calls -------------
// Packed bf16-pair input planes only. T14 async-stage: each ci-half's 10
// staging items are prefetched into registers; half1's loads are issued
// BEFORE the half0 MFMA loop so HBM latency hides under compute.
// OUTPK 1: gelu -> packed bf16 pairs. OUTPK 0: tanh -> bf16 per-voxel
// [vox][96ch], re-tiled through LDS for coalesced stores.
template<int CO, int OUTPK>
__global__ __launch_bounds__(256) void conv3_mfma(
    const uint* __restrict__ xpk,
    const uint* __restrict__ wA, const float* __restrict__ bias,
    void* __restrict__ outp)
{
  constexpr int MG = CO/16;
  constexpr int MROW = CO/32;
  __shared__ ushort xh[300*40];   // 24000 B
  int tid = threadIdx.x;
  int lane = tid & 63;
  int w = __builtin_amdgcn_readfirstlane(tid >> 6);
  int q = lane >> 4, n = lane & 15;
  int bid = blockIdx.x;           // 0..2047
  int xcd = bid & 7, islot = bid >> 3;
  int call = islot >> 7;
  int z = xcd*2 + ((islot >> 6) & 1);
  int rem = islot & 63;
  int by = (rem >> 3) << 3, bx = (rem & 7) << 3;

  const uint* xinp = xpk + (size_t)call*32*VV;

  int mbase = (w & 1) * MROW;
  int np = w >> 1;
  int lo[2];
  #pragma unroll
  for (int nt=0;nt<2;nt++){
    int vox = (np*2+nt)*16 + n;
    lo[nt] = ((vox>>3)*10 + (vox&7))*80 + q*16;
  }
  f32x4 acc[MROW][2];
  #pragma unroll
  for (int mr=0;mr<MROW;mr++)
    #pragma unroll
    for (int nt=0;nt<2;nt++){ acc[mr][nt].x=0.f; acc[mr][nt].y=0.f; acc[mr][nt].z=0.f; acc[mr][nt].w=0.f; }

  const char* ldsb = reinterpret_cast<const char*>(xh);
  const char* wac  = reinterpret_cast<const char*>(wA);

  uint pa[10], pb[10]; int lofs[10];
  auto load_half = [&](int h){
    #pragma unroll
    for (int k=0;k<10;k++){
      int it = tid + k*256;
      if (it < 2400){
        int cg = it/300; int pos = it - cg*300;
        int dz = pos/100; int rr = pos - dz*100; int dy = rr/10; int dxx = rr - dy*10;
        int gz = z + dz - 1, gy = by + dy - 1, gx = bx + dxx - 1;
        lofs[k] = pos*40 + cg*4;
        uint a = 0u, b = 0u;
        if (gz>=0 && gz<DD && gy>=0 && gy<HH && gx>=0 && gx<WW){
          size_t gv = (size_t)((gz*HH+gy)*WW + gx);
          int cp0 = h*16 + cg*2;
          a = xinp[(size_t)cp0*VV + gv];
          b = xinp[(size_t)(cp0+1)*VV + gv];
        }
        pa[k] = a; pb[k] = b;
      }
    }
  };
  auto write_half = [&](){
    #pragma unroll
    for (int k=0;k<10;k++){
      int it = tid + k*256;
      if (it < 2400){
        uint2 pk; pk.x = pa[k]; pk.y = pb[k];
        *reinterpret_cast<uint2*>(&xh[lofs[k]]) = pk;
      }
    }
  };
  auto compute_half = [&](int h){
    #pragma unroll 3
    for (int tap=0; tap<27; tap++){
      int dz = tap/9; int r9 = tap - dz*9; int dy = r9/3; int dxx = r9 - dy*3;
      int stepOff = (dz*100 + dy*10 + dxx)*80;
      int s = tap*2 + h;
      bf16x8 af[MROW];
      #pragma unroll
      for (int mr=0;mr<MROW;mr++)
        af[mr] = *reinterpret_cast<const bf16x8*>(wac + (size_t)((s*MG + mbase+mr)*64 + lane)*16);
      bf16x8 bf[2];
      #pragma unroll
      for (int nt=0;nt<2;nt++)
        bf[nt] = *reinterpret_cast<const bf16x8*>(ldsb + (lo[nt] + stepOff));
      #pragma unroll
      for (int mr=0;mr<MROW;mr++)
        #pragma unroll
        for (int nt=0;nt<2;nt++)
          acc[mr][nt] = __builtin_amdgcn_mfma_f32_16x16x32_bf16(af[mr], bf[nt], acc[mr][nt], 0, 0, 0);
    }
  };

  load_half(0);
  write_half();
  __syncthreads();
  load_half(1);          // in flight during half-0 compute
  compute_half(0);
  __syncthreads();       // all waves done reading half 0
  write_half();
  __syncthreads();
  compute_half(1);

  // epilogue: C/D col = n (voxel), row = q*4+rr (co)
  if (OUTPK == 1){
    #pragma unroll
    for (int mr=0; mr<MROW; mr++){
      int cob = (mbase+mr)*16 + q*4;
      #pragma unroll
      for (int nt=0; nt<2; nt++){
        int vox = (np*2+nt)*16 + n;
        int vy = by + (vox>>3), vx = bx + (vox&7);
        size_t gv = (size_t)((z*HH + vy)*WW + vx);
        float r0 = acc[mr][nt].x + bias[cob+0];
        float r1 = acc[mr][nt].y + bias[cob+1];
        float r2 = acc[mr][nt].z + bias[cob+2];
        float r3 = acc[mr][nt].w + bias[cob+3];
        r0 = 0.5f*r0*(1.f + erff(r0*0.70710678118654752f));
        r1 = 0.5f*r1*(1.f + erff(r1*0.70710678118654752f));
        r2 = 0.5f*r2*(1.f + erff(r2*0.70710678118654752f));
        r3 = 0.5f*r3*(1.f + erff(r3*0.70710678118654752f));
        uint* dst = (uint*)outp + (size_t)call*32*VV;
        dst[(size_t)(cob>>1)*VV + gv]     = packbf2(r0,r1);
        dst[(size_t)((cob>>1)+1)*VV + gv] = packbf2(r2,r3);
      }
    }
  } else {
    // tanh -> LDS [vox64][96ch] (12,288 B) -> coalesced row-chunk stores
    __syncthreads();
    ushort* xr = xh;
    #pragma unroll
    for (int mr=0; mr<MROW; mr++){
      int cob = (mbase+mr)*16 + q*4;
      #pragma unroll
      for (int nt=0; nt<2; nt++){
        int vox = (np*2+nt)*16 + n;
        uint2 pk;
        pk.x = packbf2(fast_tanh(acc[mr][nt].x), fast_tanh(acc[mr][nt].y));
        pk.y = packbf2(fast_tanh(acc[mr][nt].z), fast_tanh(acc[mr][nt].w));
        *reinterpret_cast<uint2*>(&xr[vox*96 + cob]) = pk;
      }
    }
    __syncthreads();
    ushort* dst = (ushort*)outp + (size_t)call*96*VV;
    const char* lb = reinterpret_cast<const char*>(xr);
    #pragma unroll
    for (int k=0; k<3; k++){
      int idx = tid + k*256;         // 768 x uint4 = 12KB
      int row = idx/96;
      int off = idx - row*96;
      size_t gb = (size_t)((z*HH + by + row)*WW + bx)*192 + (size_t)off*16;
      *reinterpret_cast<uint4*>((char*)dst + gb) = *reinterpret_cast<const uint4*>(lb + idx*16);
    }
  }
}

// ---- sampling geometry (replicates the reference's channel->axis swap) ---
struct Geom { int x0,x1,y0,y1,z0,z1; float wx,wy,wz; };
__device__ __forceinline__ Geom make_geom(float zb, float yb, float xb,
                                          float o0, float o1, float o2){
  float g0 = clampf(zb + o0*(1.f/16.f), -1.f, 1.f);
  float g1 = clampf(yb + o1*(1.f/64.f), -1.f, 1.f);
  float g2 = clampf(xb + o2*(1.f/64.f), -1.f, 1.f);
  float ix = (g0+1.f)*0.5f*63.f;    // in [0,63]
  float iy = (g1+1.f)*0.5f*63.f;
  float iz = (g2+1.f)*0.5f*15.f;    // in [0,15]
  float fx=floorf(ix), fy=floorf(iy), fz=floorf(iz);
  Geom g;
  g.wx = ix-fx; g.wy = iy-fy; g.wz = iz-fz;
  g.x0 = (int)fx; g.x1 = imin(g.x0+1, WW-1);   // float clamp bounds x0 in [0,63]
  g.y0 = (int)fy; g.y1 = imin(g.y0+1, HH-1);
  g.z0 = (int)fz; g.z1 = imin(g.z0+1, DD-1);
  return g;
}

// ---- sample + attention + MFMA out conv + BN + relu ----------------------
// 4-lane cooperative slots; z-paired volume layout: dword = (ch@z0, ch@z1)
// so each corner is 2x b128 loads + 8x v_dot2_f32_bf16 against packed
// (wyx*wz0, wyx*wz1) -> NO perms. Roles 0/1 = K, 2/3 = V.
__global__ __launch_bounds__(256) void sample_attn_kernel(
    const ushort* __restrict__ qbuf, const ushort* __restrict__ offbuf,
    const uint* __restrict__ vols, const uint* __restrict__ woA,
    const float* __restrict__ outb, const float* __restrict__ bng,
    const float* __restrict__ bnb, const float* __restrict__ bnm,
    const float* __restrict__ bnv, float* __restrict__ dout)
{
  __shared__ ushort fsb[16*72];   // fused attn output, bf16 [vox16][64ci], 144B rows
  int t = threadIdx.x;
  int lane = t & 63;
  int m = __builtin_amdgcn_readfirstlane(t >> 6);   // head
  int slot = lane >> 2;
  int r = lane & 3;
  int bid = blockIdx.x;
  int xcd = bid & 7, islot = bid >> 3;
  int call = islot >> 9;
  int z = xcd*2 + ((islot >> 8) & 1);
  int rem = islot & 255;
  int y = rem >> 2;
  int x0 = (rem & 3) << 4;
  int x = x0 + slot;
  int vbase = (z*HH + y)*WW + x0;
  int v = vbase + slot;

  const ushort* qb = qbuf   + (size_t)call*CC*VV;
  const ushort* ob = offbuf + (size_t)call*96*VV;

  // q half: roles 0/2 -> ch m*16+0..7, roles 1/3 -> +8..15 (one 16B load)
  uint4 qu = *reinterpret_cast<const uint4*>(qb + (size_t)v*64 + m*16 + (r&1)*8);
  float qf[8];
  qf[0]=bflo(qu.x); qf[1]=bfhi(qu.x); qf[2]=bflo(qu.y); qf[3]=bfhi(qu.y);
  qf[4]=bflo(qu.z); qf[5]=bfhi(qu.z); qf[6]=bflo(qu.w); qf[7]=bfhi(qu.w);

  // all 24 offsets for head m at voxel v: 3 x 16B loads
  uint ou[12];
  {
    const uint4* op4 = reinterpret_cast<const uint4*>(ob + (size_t)v*96 + m*24);
    uint4 a = op4[0], b4 = op4[1], c4 = op4[2];
    ou[0]=a.x;  ou[1]=a.y;  ou[2]=a.z;  ou[3]=a.w;
    ou[4]=b4.x; ou[5]=b4.y; ou[6]=b4.z; ou[7]=b4.w;
    ou[8]=c4.x; ou[9]=c4.y; ou[10]=c4.z; ou[11]=c4.w;
  }

  float zbf = -1.f + (float)z*(2.f/15.f);
  float ybf = -1.f + (float)y*(2.f/63.f);
  float xbf = -1.f + (float)x*(2.f/63.f);

  // z-paired layout: per head VV*32 dwords = VV*128 bytes
  const char* volb = reinterpret_cast<const char*>(vols) + (size_t)m*VV*128;
  float roleK = (r < 2) ? 1.f : 0.f;
  float lrun = 0.f;
  float fused[8];
  #pragma unroll
  for (int c=0;c<8;c++) fused[c]=0.f;

  #pragma unroll
  for (int s=0;s<NSAMP;s++){
    int i0 = 3*s, i1 = 3*s+1, i2 = 3*s+2;          // static after unroll
    float o0 = (i0&1) ? bfhi(ou[i0>>1]) : bflo(ou[i0>>1]);
    float o1 = (i1&1) ? bfhi(ou[i1>>1]) : bflo(ou[i1>>1]);
    float o2 = (i2&1) ? bfhi(ou[i2>>1]) : bflo(ou[i2>>1]);
    Geom g = make_geom(zbf,ybf,xbf,o0,o1,o2);
    const char* pz = volb + (g.z0*128 + r*32);
    float wx1 = g.wx, wx0 = 1.f-g.wx;
    float wy1 = g.wy, wy0 = 1.f-g.wy;
    float wz1 = g.wz, wz0 = 1.f-g.wz;
    float acc[8];
    #pragma unroll
    for (int c=0;c<8;c++) acc[c]=0.f;
    #pragma unroll
    for (int ky=0;ky<2;ky++)
    #pragma unroll
    for (int kx=0;kx<2;kx++){
      int cy = ky? g.y1:g.y0, cx = kx? g.x1:g.x0;
      float wyx = (ky? wy1:wy0)*(kx? wx1:wx0);
      float a0 = wyx*wz0, a1 = wyx*wz1;
      uint wzp;
      asm("v_cvt_pk_bf16_f32 %0, %1, %2" : "=v"(wzp) : "v"(a0), "v"(a1));
      const char* p = pz + (((cy<<6) + cx) << 11);
      uint4 u0 = *reinterpret_cast<const uint4*>(p);
      uint4 u1 = *reinterpret_cast<const uint4*>(p + 16);
      asm("v_dot2_f32_bf16 %0, %1, %2, %0" : "+v"(acc[0]) : "v"(u0.x), "v"(wzp));
      asm("v_dot2_f32_bf16 %0, %1, %2, %0" : "+v"(acc[1]) : "v"(u0.y), "v"(wzp));
      asm("v_dot2_f32_bf16 %0, %1, %2, %0" : "+v"(acc[2]) : "v"(u0.z), "v"(wzp));
      asm("v_dot2_f32_bf16 %0, %1, %2, %0" : "+v"(acc[3]) : "v"(u0.w), "v"(wzp));
      asm("v_dot2_f32_bf16 %0, %1, %2, %0" : "+v"(acc[4]) : "v"(u1.x), "v"(wzp));
      asm("v_dot2_f32_bf16 %0, %1, %2, %0" : "+v"(acc[5]) : "v"(u1.y), "v"(wzp));
      asm("v_dot2_f32_bf16 %0, %1, %2, %0" : "+v"(acc[6]) : "v"(u1.z), "v"(wzp));
      asm("v_dot2_f32_bf16 %0, %1, %2, %0" : "+v"(acc[7]) : "v"(u1.w), "v"(wzp));
    }
    float h = qf[0]*acc[0]+qf[1]*acc[1]+qf[2]*acc[2]+qf[3]*acc[3]
            + qf[4]*acc[4]+qf[5]*acc[5]+qf[6]*acc[6]+qf[7]*acc[7];
    h *= roleK;                 // roles 2/3 contribute 0
    h += __shfl_xor(h, 1);      // sum K halves within role pair
    h += __shfl_xor(h, 2);      // broadcast to V lanes
    float e = __expf(h);
    lrun += e;
    #pragma unroll
    for (int c=0;c<8;c++) fused[c] += e*acc[c];
  }
  float isum = 1.f/lrun;
  if (r >= 2){
    uint4 pk;
    pk.x = packbf2(fused[0]*isum, fused[1]*isum);
    pk.y = packbf2(fused[2]*isum, fused[3]*isum);
    pk.z = packbf2(fused[4]*isum, fused[5]*isum);
    pk.w = packbf2(fused[6]*isum, fused[7]*isum);
    *reinterpret_cast<uint4*>(&fsb[slot*72 + m*16 + (r&1)*8]) = pk;
  }
  __syncthreads();

  // out 1x1 conv via MFMA: wave m computes co-tile m (16 co) x 16 vox
  int qq = lane >> 4, n = lane & 15;
  f32x4 acco;
  acco.x=0.f; acco.y=0.f; acco.z=0.f; acco.w=0.f;
  const char* ldsb = reinterpret_cast<const char*>(fsb);
  const char* wac  = reinterpret_cast<const char*>(woA);
  #pragma unroll
  for (int ks=0; ks<2; ks++){
    bf16x8 af = *reinterpret_cast<const bf16x8*>(wac + (size_t)((ks*4 + m)*64 + lane)*16);
    bf16x8 bfv = *reinterpret_cast<const bf16x8*>(ldsb + (n*144 + qq*16 + ks*64));
    acco = __builtin_amdgcn_mfma_f32_16x16x32_bf16(af, bfv, acco, 0, 0, 0);
  }
  int choff = 64 + call*64;
  #pragma unroll
  for (int rr=0; rr<4; rr++){
    int co = m*16 + qq*4 + rr;
    float inv = rsqrtf(bnv[co] + 1e-5f) * bng[co];
    float val = (acco[rr] + outb[co] - bnm[co]) * inv + bnb[co];
    val = fmaxf(val, 0.f);
    dout[(size_t)(choff+co)*VV + vbase + n] = val;
  }
}

extern "C" void kernel_launch(void* const* d_in, const int* in_sizes, int n_in,
                              void* d_out, int out_size, void* d_ws, size_t ws_size,
                              hipStream_t stream){
  (void)in_sizes; (void)n_in; (void)out_size; (void)ws_size;
  const float* mid  = (const float*)d_in[0];
  const float* occ  = (const float*)d_in[1];
  const float* prev = (const float*)d_in[2];
  const float* off1w= (const float*)d_in[3];
  const float* off1b= (const float*)d_in[4];
  const float* off2w= (const float*)d_in[5];
  const float* kvw  = (const float*)d_in[6];
  const float* kvb  = (const float*)d_in[7];
  const float* qw   = (const float*)d_in[8];
  const float* qb   = (const float*)d_in[9];
  const float* outw = (const float*)d_in[10];
  const float* outb = (const float*)d_in[11];
  const float* bng  = (const float*)d_in[12];
  const float* bnb  = (const float*)d_in[13];
  const float* bnm  = (const float*)d_in[14];
  const float* bnv  = (const float*)d_in[15];
  float* out = (float*)d_out;

  uint*   vols  = (uint*)d_ws;                          // 4*VV*16 uints   (16.8 MB)
  ushort* qbuf  = (ushort*)(vols + (size_t)4*VV*16);    // 2*64*VV ushort  (16.8 MB)
  uint*   o1pk  = (uint*)(qbuf + (size_t)2*CC*VV);      // 2*32*VV uint    (16.8 MB)
  ushort* offb  = (ushort*)(o1pk + (size_t)2*32*VV);    // 2*96*VV ushort  (25.2 MB)
  uint*   wA1   = (uint*)(offb + (size_t)2*96*VV);      // 55296
  uint*   wA2   = wA1 + 55296;                          // 82944
  uint*   wo    = wA2 + 82944;                          // 2048
  uint*   wkv   = wo  + 2048;                           // 4096
  uint*   wq    = wkv + 4096;                           // 2048
  uint*   o0pk  = wq  + 2048;                           // 2*32*VV uint    (16.8 MB)
  uint*   vols2 = o0pk + (size_t)2*32*VV;               // 4*VV*32 uint    (33.5 MB)

  pack_in<<<4096, 256, 0, stream>>>(occ, prev, o0pk);
  repack_wmfma<<<(55296+255)/256, 256, 0, stream>>>(off1w, wA1, 4);
  repack_wmfma<<<(82944+255)/256, 256, 0, stream>>>(off2w, wA2, 6);
  repack_w1mfma<<<8, 256, 0, stream>>>(outw, wo, 4);
  repack_w1mfma<<<16, 256, 0, stream>>>(kvw, wkv, 8);
  repack_w1mfma<<<8, 256, 0, stream>>>(qw, wq, 4);
  conv1_mfma<128,0><<<1024, 256, 0, stream>>>(mid, mid, wkv, kvb, (void*)vols);
  zpair<<<16384, 256, 0, stream>>>(vols, vols2);
  hipMemcpyAsync(out, mid, (size_t)CC*VV*sizeof(float), hipMemcpyDeviceToDevice, stream);
  conv1_mfma<64,1><<<2048, 256, 0, stream>>>(o0pk, nullptr, wq, qb, (void*)qbuf);
  conv3_mfma<64,1><<<2048, 256, 0, stream>>>(o0pk, wA1, off1b, (void*)o1pk);
  conv3_mfma<96,0><<<2048, 256, 0, stream>>>(o1pk, wA2, off1b, (void*)offb);
  sample_attn_kernel<<<8192, 256, 0, stream>>>(qbuf, offb, vols2, wo,
      outb, bng, bnb, bnm, bnv, out);
}

// Round 4
// 337.737 us; speedup vs baseline: 1.0917x; 1.0917x over previous
//
#include <hip/hip_runtime.h>
#include <math.h>

#define DD 16
#define HH 64
#define WW 64
#define VV (DD*HH*WW)      // 65536
#define CC 64
#define NHEADS 4
#define NSAMP 8
#define HDIM 16

typedef unsigned int uint;
typedef unsigned short ushort;
typedef __attribute__((ext_vector_type(8))) short bf16x8;
typedef __attribute__((ext_vector_type(4))) float f32x4;

__device__ __forceinline__ float clampf(float v, float lo, float hi){ return fminf(fmaxf(v, lo), hi); }
__device__ __forceinline__ int imin(int a, int b){ return a < b ? a : b; }

// bf16 helpers (RNE)
__device__ __forceinline__ ushort f2bf(float f){
  uint u = __float_as_uint(f);
  uint r = (u + 0x7fffu + ((u>>16)&1u)) >> 16;
  return (ushort)r;
}
__device__ __forceinline__ uint packbf2(float a, float b){
  return (uint)f2bf(a) | ((uint)f2bf(b) << 16);
}
__device__ __forceinline__ float bflo(uint u){ return __uint_as_float(u << 16); }
__device__ __forceinline__ float bfhi(uint u){ return __uint_as_float(u & 0xffff0000u); }
__device__ __forceinline__ float bf2f(ushort u){ return __uint_as_float((uint)u << 16); }

__device__ __forceinline__ float fast_tanh(float x){
  float e = __expf(2.f*x);
  return 1.f - 2.f/(e + 1.f);
}

// ---- input pack: occ/prev fp32 -> bf16 pair planes [call][32cp][VV] ------
__global__ __launch_bounds__(256) void pack_in(const float* __restrict__ a,
                                               const float* __restrict__ b,
                                               uint* __restrict__ o){
  int idx = blockIdx.x*256 + threadIdx.x;   // 2*32*VV/4 = 1,048,576
  int v4 = (idx & (VV/4 - 1)) * 4;
  int rest = idx >> 14;
  int cp = rest & 31;
  int call = rest >> 5;
  const float* x = call ? b : a;
  float4 f0 = *reinterpret_cast<const float4*>(x + (size_t)(2*cp)*VV + v4);
  float4 f1 = *reinterpret_cast<const float4*>(x + (size_t)(2*cp+1)*VV + v4);
  uint4 pk;
  pk.x = packbf2(f0.x, f1.x);
  pk.y = packbf2(f0.y, f1.y);
  pk.z = packbf2(f0.z, f1.z);
  pk.w = packbf2(f0.w, f1.w);
  *reinterpret_cast<uint4*>(o + (size_t)(call*32+cp)*VV + v4) = pk;
}

// ---- weight repacks ------------------------------------------------------
__global__ void repack_wmfma(const float* __restrict__ w, uint* __restrict__ o, int MG){
  int U = blockIdx.x*256 + threadIdx.x;
  int total = 54*MG*256;
  if (U >= total) return;
  int j2 = U & 3;
  int m  = (U>>2) & 15;
  int q  = (U>>6) & 3;
  int rest = U >> 8;          // s*MG + g
  int g = rest % MG;
  int s = rest / MG;
  int tap = s >> 1, h = s & 1;
  int co = g*16 + m;
  int ci = h*32 + q*8 + j2*2;
  int base = co*1728 + ci*27 + tap;
  o[U] = packbf2(w[base], w[base + 27]);
}
__global__ void repack_w1mfma(const float* __restrict__ w, uint* __restrict__ o, int MT){
  int U = blockIdx.x*256 + threadIdx.x;
  int total = 2*MT*256;
  if (U >= total) return;
  int j2 = U & 3;
  int lane = (U>>2) & 63;
  int frag = U >> 8;
  int mt = frag % MT;
  int ks = frag / MT;
  int q = lane >> 4, m = lane & 15;
  int co = mt*16 + m;
  int ci = ks*32 + q*8 + j2*2;
  o[U] = packbf2(w[co*CC + ci], w[co*CC + ci + 1]);
}

// ---- 1x1 conv via MFMA ---------------------------------------------------
// EPI 0: fp32 input (mid); +bias, pack bf16 -> vols[head][y][x][z][32ch]
// EPI 1: packed input (o0pk); (acc+bias)*0.25 -> bf16 q [call][vox][64ch]
template<int CO, int EPI>
__global__ __launch_bounds__(256) void conv1_mfma(
    const void* __restrict__ xa, const void* __restrict__ xb,
    const uint* __restrict__ wA, const float* __restrict__ bias,
    void* __restrict__ outp)
{
  constexpr int MT = CO/16;
  constexpr int MW = MT/4;
  __shared__ ushort xt[64*72];    // 9216 B
  int tid = threadIdx.x;
  int lane = tid & 63;
  int g = __builtin_amdgcn_readfirstlane(tid >> 6);
  int q = lane >> 4, n = lane & 15;
  int call = blockIdx.x >> 10;
  int v0 = (blockIdx.x & 1023) * 64;
  if constexpr (EPI == 0){
    const float* x = call ? (const float*)xb : (const float*)xa;
    for (int it = tid; it < 64*32; it += 256){
      int vox = it & 63; int cp = it >> 6;
      float a = x[(size_t)(2*cp)*VV + v0 + vox];
      float b = x[(size_t)(2*cp+1)*VV + v0 + vox];
      *reinterpret_cast<uint*>(&xt[vox*72 + 2*cp]) = packbf2(a,b);
    }
  } else {
    const uint* xp = (const uint*)xa + (size_t)call*32*VV;
    for (int it = tid; it < 64*32; it += 256){
      int vox = it & 63; int cp = it >> 6;
      *reinterpret_cast<uint*>(&xt[vox*72 + 2*cp]) = xp[(size_t)cp*VV + v0 + vox];
    }
  }
  __syncthreads();
  f32x4 acc[MW][4];
  #pragma unroll
  for (int mw=0;mw<MW;mw++)
    #pragma unroll
    for (int nt=0;nt<4;nt++){ acc[mw][nt].x=0.f; acc[mw][nt].y=0.f; acc[mw][nt].z=0.f; acc[mw][nt].w=0.f; }
  const char* ldsb = reinterpret_cast<const char*>(xt);
  const char* wac  = reinterpret_cast<const char*>(wA);
  #pragma unroll
  for (int ks=0; ks<2; ks++){
    bf16x8 bfr[4];
    #pragma unroll
    for (int nt=0; nt<4; nt++)
      bfr[nt] = *reinterpret_cast<const bf16x8*>(ldsb + ((nt*16+n)*144 + q*16 + ks*64));
    #pragma unroll
    for (int mw=0; mw<MW; mw++){
      int mt = g*MW + mw;
      bf16x8 af = *reinterpret_cast<const bf16x8*>(wac + (size_t)((ks*MT + mt)*64 + lane)*16);
      #pragma unroll
      for (int nt=0; nt<4; nt++)
        acc[mw][nt] = __builtin_amdgcn_mfma_f32_16x16x32_bf16(af, bfr[nt], acc[mw][nt], 0, 0, 0);
    }
  }
  if constexpr (EPI == 0){
    #pragma unroll
    for (int mw=0; mw<MW; mw++){
      int mt = g*MW + mw;
      int cob = mt*16 + q*4;
      #pragma unroll
      for (int nt=0; nt<4; nt++){
        int v = v0 + nt*16 + n;
        float r0 = acc[mw][nt].x + bias[cob+0];
        float r1 = acc[mw][nt].y + bias[cob+1];
        float r2 = acc[mw][nt].z + bias[cob+2];
        float r3 = acc[mw][nt].w + bias[cob+3];
        int z = v >> 12, y = (v >> 6) & 63, xx = v & 63;
        int head = cob >> 5;
        uint* vols = (uint*)outp;
        uint2 pk; pk.x = packbf2(r0,r1); pk.y = packbf2(r2,r3);
        *reinterpret_cast<uint2*>(vols + ((size_t)head*VV + (size_t)(y*WW+xx)*DD + z)*16 + ((cob&31)>>1)) = pk;
      }
    }
  } else {
    // re-tile through LDS -> coalesced 8KB linear store
    __syncthreads();
    ushort* xr = xt;            // reuse as [vox64][64ch]
    int cob = g*16 + q*4;       // MW==1
    #pragma unroll
    for (int nt=0; nt<4; nt++){
      int vox = nt*16 + n;
      uint2 pk;
      pk.x = packbf2((acc[0][nt].x + bias[cob+0])*0.25f, (acc[0][nt].y + bias[cob+1])*0.25f);
      pk.y = packbf2((acc[0][nt].z + bias[cob+2])*0.25f, (acc[0][nt].w + bias[cob+3])*0.25f);
      *reinterpret_cast<uint2*>(&xr[vox*64 + cob]) = pk;
    }
    __syncthreads();
    char* ob = (char*)((ushort*)outp + (size_t)call*CC*VV) + (size_t)v0*128;
    const char* lb = reinterpret_cast<const char*>(xr);
    #pragma unroll
    for (int k=0; k<2; k++){
      int idx = tid + k*256;    // 512 x uint4 = 8KB
      *reinterpret_cast<uint4*>(ob + idx*16) = *reinterpret_cast<const uint4*>(lb + idx*16);
    }
  }
}

// ---- 3x3x3 conv via implicit-GEMM MFMA, v2: 2-z blocks ------------------
// Block = 128 voxels (2z x 8y x 8x), halo 4x10x10 = 400 pos staged per
// ci-half (items = 8cg x 400). Waves: 2(m) x 2(n); each wave owns one
// z-slice (64 vox = 4 n-tiles) -> per tap: MROW af + 4 bf + MROW*4 MFMA.
// T14 prefetch: half1 loads issued before half0 compute. Grid 1024.
// OUTPK 1: gelu -> packed bf16 pair planes. OUTPK 0: tanh -> per-voxel
// [vox][96ch] via LDS re-tile, coalesced 1536B chunk stores.
template<int CO, int OUTPK>
__global__ __launch_bounds__(256) void conv3_mfma(
    const uint* __restrict__ xpk,
    const uint* __restrict__ wA, const float* __restrict__ bias,
    void* __restrict__ outp)
{
  constexpr int MG = CO/16;
  constexpr int MROW = CO/32;
  __shared__ ushort xh[400*40];   // 32000 B
  int tid = threadIdx.x;
  int lane = tid & 63;
  int w = __builtin_amdgcn_readfirstlane(tid >> 6);
  int q = lane >> 4, n = lane & 15;
  int bid = blockIdx.x;           // 0..1023
  int xcd = bid & 7, islot = bid >> 3;
  int call = islot >> 6;
  int z0 = xcd*2;
  int rem = islot & 63;
  int by = (rem >> 3) << 3, bx = (rem & 7) << 3;

  const uint* xinp = xpk + (size_t)call*32*VV;

  int mbase = (w & 1) * MROW;
  int nh = w >> 1;                // z-slice this wave owns
  int lo[4];
  #pragma unroll
  for (int nt=0;nt<4;nt++){
    int vl = nt*16 + n;           // 0..63 within slice
    lo[nt] = ((nh*100 + (vl>>3)*10 + (vl&7)))*80 + q*16;
  }
  f32x4 acc[MROW][4];
  #pragma unroll
  for (int mr=0;mr<MROW;mr++)
    #pragma unroll
    for (int nt=0;nt<4;nt++){ acc[mr][nt].x=0.f; acc[mr][nt].y=0.f; acc[mr][nt].z=0.f; acc[mr][nt].w=0.f; }

  const char* ldsb = reinterpret_cast<const char*>(xh);
  const char* wac  = reinterpret_cast<const char*>(wA);

  uint pa[13], pb[13];
  auto load_half = [&](int h){
    #pragma unroll
    for (int k=0;k<13;k++){
      int it = tid + k*256;
      if (it < 3200){
        int cg = it/400; int pos = it - cg*400;
        int dz = pos/100; int rr = pos - dz*100; int dy = rr/10; int dxx = rr - dy*10;
        int gz = z0 + dz - 1, gy = by + dy - 1, gx = bx + dxx - 1;
        uint a = 0u, b = 0u;
        if (gz>=0 && gz<DD && gy>=0 && gy<HH && gx>=0 && gx<WW){
          size_t gv = (size_t)((gz*HH+gy)*WW + gx);
          int cp0 = h*16 + cg*2;
          a = xinp[(size_t)cp0*VV + gv];
          b = xinp[(size_t)(cp0+1)*VV + gv];
        }
        pa[k] = a; pb[k] = b;
      }
    }
  };
  auto write_half = [&](){
    #pragma unroll
    for (int k=0;k<13;k++){
      int it = tid + k*256;
      if (it < 3200){
        int cg = it/400; int pos = it - cg*400;
        uint2 pk; pk.x = pa[k]; pk.y = pb[k];
        *reinterpret_cast<uint2*>(&xh[pos*40 + cg*4]) = pk;
      }
    }
  };
  auto compute_half = [&](int h){
    #pragma unroll 3
    for (int tap=0; tap<27; tap++){
      int dz = tap/9; int r9 = tap - dz*9; int dy = r9/3; int dxx = r9 - dy*3;
      int stepOff = (dz*100 + dy*10 + dxx)*80;
      int s = tap*2 + h;
      bf16x8 af[MROW];
      #pragma unroll
      for (int mr=0;mr<MROW;mr++)
        af[mr] = *reinterpret_cast<const bf16x8*>(wac + (size_t)((s*MG + mbase+mr)*64 + lane)*16);
      bf16x8 bf[4];
      #pragma unroll
      for (int nt=0;nt<4;nt++)
        bf[nt] = *reinterpret_cast<const bf16x8*>(ldsb + (lo[nt] + stepOff));
      #pragma unroll
      for (int mr=0;mr<MROW;mr++)
        #pragma unroll
        for (int nt=0;nt<4;nt++)
          acc[mr][nt] = __builtin_amdgcn_mfma_f32_16x16x32_bf16(af[mr], bf[nt], acc[mr][nt], 0, 0, 0);
    }
  };

  load_half(0);
  write_half();
  __syncthreads();
  load_half(1);          // in flight during half-0 compute
  compute_half(0);
  __syncthreads();       // all waves done reading half 0
  write_half();
  __syncthreads();
  compute_half(1);

  // epilogue: C/D col = n (voxel), row = q*4+rr (co)
  if (OUTPK == 1){
    #pragma unroll
    for (int mr=0; mr<MROW; mr++){
      int cob = (mbase+mr)*16 + q*4;
      #pragma unroll
      for (int nt=0; nt<4; nt++){
        int vl = nt*16 + n;
        int vy = by + (vl>>3), vx = bx + (vl&7);
        size_t gv = (size_t)(((z0+nh)*HH + vy)*WW + vx);
        float r0 = acc[mr][nt].x + bias[cob+0];
        float r1 = acc[mr][nt].y + bias[cob+1];
        float r2 = acc[mr][nt].z + bias[cob+2];
        float r3 = acc[mr][nt].w + bias[cob+3];
        r0 = 0.5f*r0*(1.f + erff(r0*0.70710678118654752f));
        r1 = 0.5f*r1*(1.f + erff(r1*0.70710678118654752f));
        r2 = 0.5f*r2*(1.f + erff(r2*0.70710678118654752f));
        r3 = 0.5f*r3*(1.f + erff(r3*0.70710678118654752f));
        uint* dst = (uint*)outp + (size_t)call*32*VV;
        dst[(size_t)(cob>>1)*VV + gv]     = packbf2(r0,r1);
        dst[(size_t)((cob>>1)+1)*VV + gv] = packbf2(r2,r3);
      }
    }
  } else {
    // tanh -> LDS [vox128][96ch] (24,576 B) -> coalesced 1536B chunk stores
    __syncthreads();
    ushort* xr = xh;
    #pragma unroll
    for (int mr=0; mr<MROW; mr++){
      int cob = (mbase+mr)*16 + q*4;
      #pragma unroll
      for (int nt=0; nt<4; nt++){
        int row = nh*64 + nt*16 + n;     // zi*64 + y8*8 + x8
        uint2 pk;
        pk.x = packbf2(fast_tanh(acc[mr][nt].x), fast_tanh(acc[mr][nt].y));
        pk.y = packbf2(fast_tanh(acc[mr][nt].z), fast_tanh(acc[mr][nt].w));
        *reinterpret_cast<uint2*>(&xr[row*96 + cob]) = pk;
      }
    }
    __syncthreads();
    ushort* dst = (ushort*)outp + (size_t)call*96*VV;
    const char* lb = reinterpret_cast<const char*>(xr);
    #pragma unroll
    for (int k=0; k<6; k++){
      int idx = tid + k*256;             // 1536 x uint4 = 24KB
      int chunk = idx/96;                // 16 chunks: (zi,y8)
      int off = idx - chunk*96;
      int zi = chunk>>3, y8 = chunk&7;
      size_t gb = (size_t)(((z0+zi)*HH + by + y8)*WW + bx)*192 + (size_t)off*16;
      *reinterpret_cast<uint4*>((char*)dst + gb) = *reinterpret_cast<const uint4*>(lb + idx*16);
    }
  }
}

// ---- sampling geometry (replicates the reference's channel->axis swap) ---
struct Geom { int x0,x1,y0,y1,z0,z1; float wx,wy,wz; };
__device__ __forceinline__ Geom make_geom(float zb, float yb, float xb,
                                          float o0, float o1, float o2){
  float g0 = clampf(zb + o0*(1.f/16.f), -1.f, 1.f);
  float g1 = clampf(yb + o1*(1.f/64.f), -1.f, 1.f);
  float g2 = clampf(xb + o2*(1.f/64.f), -1.f, 1.f);
  float ix = (g0+1.f)*0.5f*63.f;    // in [0,63]
  float iy = (g1+1.f)*0.5f*63.f;
  float iz = (g2+1.f)*0.5f*15.f;    // in [0,15]
  float fx=floorf(ix), fy=floorf(iy), fz=floorf(iz);
  Geom g;
  g.wx = ix-fx; g.wy = iy-fy; g.wz = iz-fz;
  g.x0 = (int)fx; g.x1 = imin(g.x0+1, WW-1);   // float clamp bounds x0 in [0,63]
  g.y0 = (int)fy; g.y1 = imin(g.y0+1, HH-1);
  g.z0 = (int)fz; g.z1 = imin(g.z0+1, DD-1);
  return g;
}

// ---- sample + attention + MFMA out conv + BN + relu ----------------------
// 4-lane cooperative slots; compact vols [head][y][x][z][32ch] (64B lines,
// L2-resident). Per (ky,kx) corner-pair: 2x b128 loads (z0,z1 lines),
// 8x v_perm_b32 to form (ch@z0,ch@z1) pairs, 8x v_dot2_f32_bf16 against
// packed (wyx*wz0, wyx*wz1). Roles 0/1 = K, 2/3 = V.
__global__ __launch_bounds__(256) void sample_attn_kernel(
    const ushort* __restrict__ qbuf, const ushort* __restrict__ offbuf,
    const uint* __restrict__ vols, const uint* __restrict__ woA,
    const float* __restrict__ outb, const float* __restrict__ bng,
    const float* __restrict__ bnb, const float* __restrict__ bnm,
    const float* __restrict__ bnv, float* __restrict__ dout)
{
  __shared__ ushort fsb[16*72];   // fused attn output, bf16 [vox16][64ci], 144B rows
  int t = threadIdx.x;
  int lane = t & 63;
  int m = __builtin_amdgcn_readfirstlane(t >> 6);   // head
  int slot = lane >> 2;
  int r = lane & 3;
  int bid = blockIdx.x;
  int xcd = bid & 7, islot = bid >> 3;
  int call = islot >> 9;
  int z = xcd*2 + ((islot >> 8) & 1);
  int rem = islot & 255;
  int y = rem >> 2;
  int x0 = (rem & 3) << 4;
  int x = x0 + slot;
  int vbase = (z*HH + y)*WW + x0;
  int v = vbase + slot;

  const ushort* qb = qbuf   + (size_t)call*CC*VV;
  const ushort* ob = offbuf + (size_t)call*96*VV;

  // q half: roles 0/2 -> ch m*16+0..7, roles 1/3 -> +8..15 (one 16B load)
  uint4 qu = *reinterpret_cast<const uint4*>(qb + (size_t)v*64 + m*16 + (r&1)*8);
  float qf[8];
  qf[0]=bflo(qu.x); qf[1]=bfhi(qu.x); qf[2]=bflo(qu.y); qf[3]=bfhi(qu.y);
  qf[4]=bflo(qu.z); qf[5]=bfhi(qu.z); qf[6]=bflo(qu.w); qf[7]=bfhi(qu.w);

  // all 24 offsets for head m at voxel v: 3 x 16B loads
  uint ou[12];
  {
    const uint4* op4 = reinterpret_cast<const uint4*>(ob + (size_t)v*96 + m*24);
    uint4 a = op4[0], b4 = op4[1], c4 = op4[2];
    ou[0]=a.x;  ou[1]=a.y;  ou[2]=a.z;  ou[3]=a.w;
    ou[4]=b4.x; ou[5]=b4.y; ou[6]=b4.z; ou[7]=b4.w;
    ou[8]=c4.x; ou[9]=c4.y; ou[10]=c4.z; ou[11]=c4.w;
  }

  float zbf = -1.f + (float)z*(2.f/15.f);
  float ybf = -1.f + (float)y*(2.f/63.f);
  float xbf = -1.f + (float)x*(2.f/63.f);

  const char* volb = reinterpret_cast<const char*>(vols) + (size_t)m*VV*64;
  float roleK = (r < 2) ? 1.f : 0.f;
  float lrun = 0.f;
  float fused[8];
  #pragma unroll
  for (int c=0;c<8;c++) fused[c]=0.f;

  #pragma unroll
  for (int s=0;s<NSAMP;s++){
    int i0 = 3*s, i1 = 3*s+1, i2 = 3*s+2;          // static after unroll
    float o0 = (i0&1) ? bfhi(ou[i0>>1]) : bflo(ou[i0>>1]);
    float o1 = (i1&1) ? bfhi(ou[i1>>1]) : bflo(ou[i1>>1]);
    float o2 = (i2&1) ? bfhi(ou[i2>>1]) : bflo(ou[i2>>1]);
    Geom g = make_geom(zbf,ybf,xbf,o0,o1,o2);
    int tz0 = g.z0*64 + r*16;
    int tz1 = g.z1*64 + r*16;
    float wx1 = g.wx, wx0 = 1.f-g.wx;
    float wy1 = g.wy, wy0 = 1.f-g.wy;
    float wz1 = g.wz, wz0 = 1.f-g.wz;
    float acc[8];
    #pragma unroll
    for (int c=0;c<8;c++) acc[c]=0.f;
    #pragma unroll
    for (int ky=0;ky<2;ky++)
    #pragma unroll
    for (int kx=0;kx<2;kx++){
      int cy = ky? g.y1:g.y0, cx = kx? g.x1:g.x0;
      float wyx = (ky? wy1:wy0)*(kx? wx1:wx0);
      float a0 = wyx*wz0, a1 = wyx*wz1;
      uint wzp;
      asm("v_cvt_pk_bf16_f32 %0, %1, %2" : "=v"(wzp) : "v"(a0), "v"(a1));
      int tb = ((cy<<6) + cx) << 10;
      const char* p = volb + tb;
      uint4 u0 = *reinterpret_cast<const uint4*>(p + tz0);
      uint4 u1 = *reinterpret_cast<const uint4*>(p + tz1);
      uint plo, phi;
      plo = __builtin_amdgcn_perm(u1.x, u0.x, 0x05040100u);
      phi = __builtin_amdgcn_perm(u1.x, u0.x, 0x07060302u);
      asm("v_dot2_f32_bf16 %0, %1, %2, %0" : "+v"(acc[0]) : "v"(plo), "v"(wzp));
      asm("v_dot2_f32_bf16 %0, %1, %2, %0" : "+v"(acc[1]) : "v"(phi), "v"(wzp));
      plo = __builtin_amdgcn_perm(u1.y, u0.y, 0x05040100u);
      phi = __builtin_amdgcn_perm(u1.y, u0.y, 0x07060302u);
      asm("v_dot2_f32_bf16 %0, %1, %2, %0" : "+v"(acc[2]) : "v"(plo), "v"(wzp));
      asm("v_dot2_f32_bf16 %0, %1, %2, %0" : "+v"(acc[3]) : "v"(phi), "v"(wzp));
      plo = __builtin_amdgcn_perm(u1.z, u0.z, 0x05040100u);
      phi = __builtin_amdgcn_perm(u1.z, u0.z, 0x07060302u);
      asm("v_dot2_f32_bf16 %0, %1, %2, %0" : "+v"(acc[4]) : "v"(plo), "v"(wzp));
      asm("v_dot2_f32_bf16 %0, %1, %2, %0" : "+v"(acc[5]) : "v"(phi), "v"(wzp));
      plo = __builtin_amdgcn_perm(u1.w, u0.w, 0x05040100u);
      phi = __builtin_amdgcn_perm(u1.w, u0.w, 0x07060302u);
      asm("v_dot2_f32_bf16 %0, %1, %2, %0" : "+v"(acc[6]) : "v"(plo), "v"(wzp));
      asm("v_dot2_f32_bf16 %0, %1, %2, %0" : "+v"(acc[7]) : "v"(phi), "v"(wzp));
    }
    float h = qf[0]*acc[0]+qf[1]*acc[1]+qf[2]*acc[2]+qf[3]*acc[3]
            + qf[4]*acc[4]+qf[5]*acc[5]+qf[6]*acc[6]+qf[7]*acc[7];
    h *= roleK;                 // roles 2/3 contribute 0
    h += __shfl_xor(h, 1);      // sum K halves within role pair
    h += __shfl_xor(h, 2);      // broadcast to V lanes
    float e = __expf(h);
    lrun += e;
    #pragma unroll
    for (int c=0;c<8;c++) fused[c] += e*acc[c];
  }
  float isum = 1.f/lrun;
  if (r >= 2){
    uint4 pk;
    pk.x = packbf2(fused[0]*isum, fused[1]*isum);
    pk.y = packbf2(fused[2]*isum, fused[3]*isum);
    pk.z = packbf2(fused[4]*isum, fused[5]*isum);
    pk.w = packbf2(fused[6]*isum, fused[7]*isum);
    *reinterpret_cast<uint4*>(&fsb[slot*72 + m*16 + (r&1)*8]) = pk;
  }
  __syncthreads();

  // out 1x1 conv via MFMA: wave m computes co-tile m (16 co) x 16 vox
  int qq = lane >> 4, n = lane & 15;
  f32x4 acco;
  acco.x=0.f; acco.y=0.f; acco.z=0.f; acco.w=0.f;
  const char* ldsb = reinterpret_cast<const char*>(fsb);
  const char* wac  = reinterpret_cast<const char*>(woA);
  #pragma unroll
  for (int ks=0; ks<2; ks++){
    bf16x8 af = *reinterpret_cast<const bf16x8*>(wac + (size_t)((ks*4 + m)*64 + lane)*16);
    bf16x8 bfv = *reinterpret_cast<const bf16x8*>(ldsb + (n*144 + qq*16 + ks*64));
    acco = __builtin_amdgcn_mfma_f32_16x16x32_bf16(af, bfv, acco, 0, 0, 0);
  }
  int choff = 64 + call*64;
  #pragma unroll
  for (int rr=0; rr<4; rr++){
    int co = m*16 + qq*4 + rr;
    float inv = rsqrtf(bnv[co] + 1e-5f) * bng[co];
    float val = (acco[rr] + outb[co] - bnm[co]) * inv + bnb[co];
    val = fmaxf(val, 0.f);
    dout[(size_t)(choff+co)*VV + vbase + n] = val;
  }
}

extern "C" void kernel_launch(void* const* d_in, const int* in_sizes, int n_in,
                              void* d_out, int out_size, void* d_ws, size_t ws_size,
                              hipStream_t stream){
  (void)in_sizes; (void)n_in; (void)out_size; (void)ws_size;
  const float* mid  = (const float*)d_in[0];
  const float* occ  = (const float*)d_in[1];
  const float* prev = (const float*)d_in[2];
  const float* off1w= (const float*)d_in[3];
  const float* off1b= (const float*)d_in[4];
  const float* off2w= (const float*)d_in[5];
  const float* kvw  = (const float*)d_in[6];
  const float* kvb  = (const float*)d_in[7];
  const float* qw   = (const float*)d_in[8];
  const float* qb   = (const float*)d_in[9];
  const float* outw = (const float*)d_in[10];
  const float* outb = (const float*)d_in[11];
  const float* bng  = (const float*)d_in[12];
  const float* bnb  = (const float*)d_in[13];
  const float* bnm  = (const float*)d_in[14];
  const float* bnv  = (const float*)d_in[15];
  float* out = (float*)d_out;

  uint*   vols  = (uint*)d_ws;                          // 4*VV*16 uints   (16.8 MB)
  ushort* qbuf  = (ushort*)(vols + (size_t)4*VV*16);    // 2*64*VV ushort  (16.8 MB)
  uint*   o1pk  = (uint*)(qbuf + (size_t)2*CC*VV);      // 2*32*VV uint    (16.8 MB)
  ushort* offb  = (ushort*)(o1pk + (size_t)2*32*VV);    // 2*96*VV ushort  (25.2 MB)
  uint*   wA1   = (uint*)(offb + (size_t)2*96*VV);      // 55296
  uint*   wA2   = wA1 + 55296;                          // 82944
  uint*   wo    = wA2 + 82944;                          // 2048
  uint*   wkv   = wo  + 2048;                           // 4096
  uint*   wq    = wkv + 4096;                           // 2048
  uint*   o0pk  = wq  + 2048;                           // 2*32*VV uint    (16.8 MB)

  pack_in<<<4096, 256, 0, stream>>>(occ, prev, o0pk);
  repack_wmfma<<<(55296+255)/256, 256, 0, stream>>>(off1w, wA1, 4);
  repack_wmfma<<<(82944+255)/256, 256, 0, stream>>>(off2w, wA2, 6);
  repack_w1mfma<<<8, 256, 0, stream>>>(outw, wo, 4);
  repack_w1mfma<<<16, 256, 0, stream>>>(kvw, wkv, 8);
  repack_w1mfma<<<8, 256, 0, stream>>>(qw, wq, 4);
  conv1_mfma<128,0><<<1024, 256, 0, stream>>>(mid, mid, wkv, kvb, (void*)vols);
  hipMemcpyAsync(out, mid, (size_t)CC*VV*sizeof(float), hipMemcpyDeviceToDevice, stream);
  conv1_mfma<64,1><<<2048, 256, 0, stream>>>(o0pk, nullptr, wq, qb, (void*)qbuf);
  conv3_mfma<64,1><<<1024, 256, 0, stream>>>(o0pk, wA1, off1b, (void*)o1pk);
  conv3_mfma<96,0><<<1024, 256, 0, stream>>>(o1pk, wA2, off1b, (void*)offb);
  sample_attn_kernel<<<8192, 256, 0, stream>>>(qbuf, offb, vols, wo,
      outb, bng, bnb, bnm, bnv, out);
}

// Round 5
// 327.603 us; speedup vs baseline: 1.1255x; 1.0309x over previous
//
#include <hip/hip_runtime.h>
#include <math.h>

#define DD 16
#define HH 64
#define WW 64
#define VV (DD*HH*WW)      // 65536
#define CC 64
#define NHEADS 4
#define NSAMP 8
#define HDIM 16

typedef unsigned int uint;
typedef unsigned short ushort;
typedef __attribute__((ext_vector_type(8))) short bf16x8;
typedef __attribute__((ext_vector_type(4))) float f32x4;

__device__ __forceinline__ float clampf(float v, float lo, float hi){ return fminf(fmaxf(v, lo), hi); }
__device__ __forceinline__ int imin(int a, int b){ return a < b ? a : b; }

// bf16 helpers (RNE)
__device__ __forceinline__ ushort f2bf(float f){
  uint u = __float_as_uint(f);
  uint r = (u + 0x7fffu + ((u>>16)&1u)) >> 16;
  return (ushort)r;
}
__device__ __forceinline__ uint packbf2(float a, float b){
  return (uint)f2bf(a) | ((uint)f2bf(b) << 16);
}
__device__ __forceinline__ float bflo(uint u){ return __uint_as_float(u << 16); }
__device__ __forceinline__ float bfhi(uint u){ return __uint_as_float(u & 0xffff0000u); }
__device__ __forceinline__ float bf2f(ushort u){ return __uint_as_float((uint)u << 16); }

__device__ __forceinline__ float fast_tanh(float x){
  float e = __expf(2.f*x);
  return 1.f - 2.f/(e + 1.f);
}

// ---- weight repack bodies ------------------------------------------------
__device__ __forceinline__ void repack_wmfma_body(const float* __restrict__ w,
                                                  uint* __restrict__ o, int MG, int U){
  int j2 = U & 3;
  int m  = (U>>2) & 15;
  int q  = (U>>6) & 3;
  int rest = U >> 8;          // s*MG + g
  int g = rest % MG;
  int s = rest / MG;
  int tap = s >> 1, h = s & 1;
  int co = g*16 + m;
  int ci = h*32 + q*8 + j2*2;
  int base = co*1728 + ci*27 + tap;
  o[U] = packbf2(w[base], w[base + 27]);
}
__device__ __forceinline__ void repack_w1_body(const float* __restrict__ w,
                                               uint* __restrict__ o, int MT, int U){
  int j2 = U & 3;
  int lane = (U>>2) & 63;
  int frag = U >> 8;
  int mt = frag % MT;
  int ks = frag / MT;
  int q = lane >> 4, m = lane & 15;
  int co = mt*16 + m;
  int ci = ks*32 + q*8 + j2*2;
  o[U] = packbf2(w[co*CC + ci], w[co*CC + ci + 1]);
}

// ---- prep: input quad-pack + all weight repacks in one launch ------------
// blocks [0,2048): occ/prev fp32 -> quad planes o0pk[call][16cq][VV] uint2
//   (uint2 = (packbf2(c0,c1), packbf2(c2,c3)) for ci quad cq*4..cq*4+3)
// blocks [2048,2264): wA1   [2264,2588): wA2
// [2588,2596): wo  [2596,2612): wkv  [2612,2620): wq
__global__ __launch_bounds__(256) void prep(
    const float* __restrict__ occ, const float* __restrict__ prev,
    uint* __restrict__ o0pk,
    const float* __restrict__ off1w, uint* __restrict__ wA1,
    const float* __restrict__ off2w, uint* __restrict__ wA2,
    const float* __restrict__ outw, uint* __restrict__ wo,
    const float* __restrict__ kvw,  uint* __restrict__ wkv,
    const float* __restrict__ qw,   uint* __restrict__ wq)
{
  int b = blockIdx.x, tid = threadIdx.x;
  if (b < 2048){
    int idx = b*256 + tid;                // 2*16*VV/4 = 524288
    int v4 = (idx & (VV/4 - 1)) * 4;
    int rest = idx >> 14;
    int cq = rest & 15;
    int call = rest >> 4;
    const float* x = call ? prev : occ;
    const float* p0 = x + (size_t)(cq*4)*VV + v4;
    float4 f0 = *reinterpret_cast<const float4*>(p0);
    float4 f1 = *reinterpret_cast<const float4*>(p0 + VV);
    float4 f2 = *reinterpret_cast<const float4*>(p0 + 2*VV);
    float4 f3 = *reinterpret_cast<const float4*>(p0 + 3*VV);
    uint* ob = o0pk + ((size_t)(call*16 + cq)*VV + v4)*2;
    uint4 w0, w1;
    w0.x = packbf2(f0.x, f1.x); w0.y = packbf2(f2.x, f3.x);
    w0.z = packbf2(f0.y, f1.y); w0.w = packbf2(f2.y, f3.y);
    w1.x = packbf2(f0.z, f1.z); w1.y = packbf2(f2.z, f3.z);
    w1.z = packbf2(f0.w, f1.w); w1.w = packbf2(f2.w, f3.w);
    *reinterpret_cast<uint4*>(ob)     = w0;
    *reinterpret_cast<uint4*>(ob + 4) = w1;
  }
  else if (b < 2264){ repack_wmfma_body(off1w, wA1, 4, (b-2048)*256 + tid); }
  else if (b < 2588){ repack_wmfma_body(off2w, wA2, 6, (b-2264)*256 + tid); }
  else if (b < 2596){ repack_w1_body(outw, wo, 4, (b-2588)*256 + tid); }
  else if (b < 2612){ repack_w1_body(kvw, wkv, 8, (b-2596)*256 + tid); }
  else              { repack_w1_body(qw,  wq, 4, (b-2612)*256 + tid); }
}

// ---- 1x1 conv via MFMA ---------------------------------------------------
// EPI 0: fp32 input (mid); +bias, pack bf16 -> vols[head][y][x][z][32ch];
//        also copies mid -> mcopy (folds the out[0:64] memcpy).
// EPI 1: quad-packed input; (acc+bias)*0.25 -> bf16 q [call][vox][64ch]
template<int CO, int EPI>
__global__ __launch_bounds__(256) void conv1_mfma(
    const float* __restrict__ xf, const uint* __restrict__ xq,
    const uint* __restrict__ wA, const float* __restrict__ bias,
    void* __restrict__ outp, float* __restrict__ mcopy)
{
  constexpr int MT = CO/16;
  constexpr int MW = MT/4;
  __shared__ ushort xt[64*72];    // 9216 B
  int tid = threadIdx.x;
  int lane = tid & 63;
  int g = __builtin_amdgcn_readfirstlane(tid >> 6);
  int q = lane >> 4, n = lane & 15;
  int call = blockIdx.x >> 10;
  int v0 = (blockIdx.x & 1023) * 64;
  if constexpr (EPI == 0){
    for (int it = tid; it < 64*32; it += 256){
      int vox = it & 63; int cp = it >> 6;
      float a = xf[(size_t)(2*cp)*VV + v0 + vox];
      float b = xf[(size_t)(2*cp+1)*VV + v0 + vox];
      mcopy[(size_t)(2*cp)*VV + v0 + vox] = a;
      mcopy[(size_t)(2*cp+1)*VV + v0 + vox] = b;
      *reinterpret_cast<uint*>(&xt[vox*72 + 2*cp]) = packbf2(a,b);
    }
  } else {
    const uint2* xp = reinterpret_cast<const uint2*>(xq) + (size_t)call*16*VV;
    for (int it = tid; it < 64*16; it += 256){
      int vox = it & 63; int cq = it >> 6;
      *reinterpret_cast<uint2*>(&xt[vox*72 + cq*4]) = xp[(size_t)cq*VV + v0 + vox];
    }
  }
  __syncthreads();
  f32x4 acc[MW][4];
  #pragma unroll
  for (int mw=0;mw<MW;mw++)
    #pragma unroll
    for (int nt=0;nt<4;nt++){ acc[mw][nt].x=0.f; acc[mw][nt].y=0.f; acc[mw][nt].z=0.f; acc[mw][nt].w=0.f; }
  const char* ldsb = reinterpret_cast<const char*>(xt);
  const char* wac  = reinterpret_cast<const char*>(wA);
  #pragma unroll
  for (int ks=0; ks<2; ks++){
    bf16x8 bfr[4];
    #pragma unroll
    for (int nt=0; nt<4; nt++)
      bfr[nt] = *reinterpret_cast<const bf16x8*>(ldsb + ((nt*16+n)*144 + q*16 + ks*64));
    #pragma unroll
    for (int mw=0; mw<MW; mw++){
      int mt = g*MW + mw;
      bf16x8 af = *reinterpret_cast<const bf16x8*>(wac + (size_t)((ks*MT + mt)*64 + lane)*16);
      #pragma unroll
      for (int nt=0; nt<4; nt++)
        acc[mw][nt] = __builtin_amdgcn_mfma_f32_16x16x32_bf16(af, bfr[nt], acc[mw][nt], 0, 0, 0);
    }
  }
  if constexpr (EPI == 0){
    #pragma unroll
    for (int mw=0; mw<MW; mw++){
      int mt = g*MW + mw;
      int cob = mt*16 + q*4;
      #pragma unroll
      for (int nt=0; nt<4; nt++){
        int v = v0 + nt*16 + n;
        float r0 = acc[mw][nt].x + bias[cob+0];
        float r1 = acc[mw][nt].y + bias[cob+1];
        float r2 = acc[mw][nt].z + bias[cob+2];
        float r3 = acc[mw][nt].w + bias[cob+3];
        int z = v >> 12, y = (v >> 6) & 63, xx = v & 63;
        int head = cob >> 5;
        uint* vols = (uint*)outp;
        uint2 pk; pk.x = packbf2(r0,r1); pk.y = packbf2(r2,r3);
        *reinterpret_cast<uint2*>(vols + ((size_t)head*VV + (size_t)(y*WW+xx)*DD + z)*16 + ((cob&31)>>1)) = pk;
      }
    }
  } else {
    // re-tile through LDS -> coalesced 8KB linear store
    __syncthreads();
    ushort* xr = xt;            // reuse as [vox64][64ch]
    int cob = g*16 + q*4;       // MW==1
    #pragma unroll
    for (int nt=0; nt<4; nt++){
      int vox = nt*16 + n;
      uint2 pk;
      pk.x = packbf2((acc[0][nt].x + bias[cob+0])*0.25f, (acc[0][nt].y + bias[cob+1])*0.25f);
      pk.y = packbf2((acc[0][nt].z + bias[cob+2])*0.25f, (acc[0][nt].w + bias[cob+3])*0.25f);
      *reinterpret_cast<uint2*>(&xr[vox*64 + cob]) = pk;
    }
    __syncthreads();
    char* ob = (char*)((ushort*)outp + (size_t)call*CC*VV) + (size_t)v0*128;
    const char* lb = reinterpret_cast<const char*>(xr);
    #pragma unroll
    for (int k=0; k<2; k++){
      int idx = tid + k*256;    // 512 x uint4 = 8KB
      *reinterpret_cast<uint4*>(ob + idx*16) = *reinterpret_cast<const uint4*>(lb + idx*16);
    }
  }
}

// ---- 3x3x3 conv via implicit-GEMM MFMA, v3: 4-z blocks ------------------
// Block = 256 voxels (4z x 8y x 8x), halo 6x10x10 = 600 pos per ci-half
// (items = 8cq x 600, one uint2 each from quad-packed planes). Waves:
// 2(m) x 2(z-pair); each wave owns 2 z-slices = 8 n-tiles -> per tap:
// MROW af + 8 bf + MROW*8 MFMA (2x weight reuse vs v2). T14 prefetch:
// half1 loads issued before half0 compute. Grid 512.
// OUTPK 1: gelu -> quad-packed planes. OUTPK 0: tanh -> per-voxel
// [vox][96ch] via LDS re-tile, coalesced 1536B chunk stores.
template<int CO, int OUTPK>
__global__ __launch_bounds__(256) void conv3_mfma(
    const uint* __restrict__ xpk,
    const uint* __restrict__ wA, const float* __restrict__ bias,
    void* __restrict__ outp)
{
  constexpr int MG = CO/16;
  constexpr int MROW = CO/32;
  __shared__ ushort xh[24576];   // 49152 B (staging uses 48000)
  int tid = threadIdx.x;
  int lane = tid & 63;
  int w = __builtin_amdgcn_readfirstlane(tid >> 6);
  int q = lane >> 4, n = lane & 15;
  int bid = blockIdx.x;           // 0..511
  int xcd = bid & 7, islot = bid >> 3;     // islot 0..63 = (by,bx)
  int call = xcd >> 2;
  int z0 = (xcd & 3) * 4;
  int by = (islot >> 3) << 3, bx = (islot & 7) << 3;

  const uint2* xinp = reinterpret_cast<const uint2*>(xpk) + (size_t)call*16*VV;

  int mbase = (w & 1) * MROW;
  int nzh = (w >> 1) * 2;         // first local z-slice owned by this wave
  int lo[8];
  #pragma unroll
  for (int nt=0;nt<8;nt++){
    int zi = nzh + (nt>>2);
    int vl = (nt&3)*16 + n;       // 0..63 within slice
    lo[nt] = (zi*100 + (vl>>3)*10 + (vl&7))*80 + q*16;
  }
  f32x4 acc[MROW][8];
  #pragma unroll
  for (int mr=0;mr<MROW;mr++)
    #pragma unroll
    for (int nt=0;nt<8;nt++){ acc[mr][nt].x=0.f; acc[mr][nt].y=0.f; acc[mr][nt].z=0.f; acc[mr][nt].w=0.f; }

  const char* ldsb = reinterpret_cast<const char*>(xh);
  const char* wac  = reinterpret_cast<const char*>(wA);

  uint2 pq[19];
  auto load_half = [&](int h){
    #pragma unroll
    for (int k=0;k<19;k++){
      int it = tid + k*256;
      if (it < 4800){
        int cg = it/600; int pos = it - cg*600;
        int dz = pos/100; int rr = pos - dz*100; int dy = rr/10; int dxx = rr - dy*10;
        int gz = z0 + dz - 1, gy = by + dy - 1, gx = bx + dxx - 1;
        uint2 v; v.x = 0u; v.y = 0u;
        if (gz>=0 && gz<DD && gy>=0 && gy<HH && gx>=0 && gx<WW)
          v = xinp[(size_t)(h*8+cg)*VV + (size_t)((gz*HH+gy)*WW + gx)];
        pq[k] = v;
      }
    }
  };
  auto write_half = [&](){
    #pragma unroll
    for (int k=0;k<19;k++){
      int it = tid + k*256;
      if (it < 4800){
        int cg = it/600; int pos = it - cg*600;
        *reinterpret_cast<uint2*>(&xh[pos*40 + cg*4]) = pq[k];
      }
    }
  };
  auto compute_half = [&](int h){
    #pragma unroll 2
    for (int tap=0; tap<27; tap++){
      int dz = tap/9; int r9 = tap - dz*9; int dy = r9/3; int dxx = r9 - dy*3;
      int stepOff = (dz*100 + dy*10 + dxx)*80;
      int s = tap*2 + h;
      bf16x8 af[MROW];
      #pragma unroll
      for (int mr=0;mr<MROW;mr++)
        af[mr] = *reinterpret_cast<const bf16x8*>(wac + (size_t)((s*MG + mbase+mr)*64 + lane)*16);
      bf16x8 bf[8];
      #pragma unroll
      for (int nt=0;nt<8;nt++)
        bf[nt] = *reinterpret_cast<const bf16x8*>(ldsb + (lo[nt] + stepOff));
      #pragma unroll
      for (int mr=0;mr<MROW;mr++)
        #pragma unroll
        for (int nt=0;nt<8;nt++)
          acc[mr][nt] = __builtin_amdgcn_mfma_f32_16x16x32_bf16(af[mr], bf[nt], acc[mr][nt], 0, 0, 0);
    }
  };

  load_half(0);
  write_half();
  __syncthreads();
  load_half(1);          // in flight during half-0 compute
  compute_half(0);
  __syncthreads();       // all waves done reading half 0
  write_half();
  __syncthreads();
  compute_half(1);

  // epilogue: C/D col = n (voxel), row = q*4+rr (co)
  if (OUTPK == 1){
    #pragma unroll
    for (int mr=0; mr<MROW; mr++){
      int cob = (mbase+mr)*16 + q*4;
      #pragma unroll
      for (int nt=0; nt<8; nt++){
        int zi = nzh + (nt>>2);
        int vl = (nt&3)*16 + n;
        int vy = by + (vl>>3), vx = bx + (vl&7);
        size_t gv = (size_t)(((z0+zi)*HH + vy)*WW + vx);
        float r0 = acc[mr][nt].x + bias[cob+0];
        float r1 = acc[mr][nt].y + bias[cob+1];
        float r2 = acc[mr][nt].z + bias[cob+2];
        float r3 = acc[mr][nt].w + bias[cob+3];
        r0 = 0.5f*r0*(1.f + erff(r0*0.70710678118654752f));
        r1 = 0.5f*r1*(1.f + erff(r1*0.70710678118654752f));
        r2 = 0.5f*r2*(1.f + erff(r2*0.70710678118654752f));
        r3 = 0.5f*r3*(1.f + erff(r3*0.70710678118654752f));
        uint2 pk; pk.x = packbf2(r0,r1); pk.y = packbf2(r2,r3);
        uint* dst = (uint*)outp;
        *reinterpret_cast<uint2*>(dst + ((size_t)(call*16 + (cob>>2))*VV + gv)*2) = pk;
      }
    }
  } else {
    // tanh -> LDS [vox256][96ch] (49,152 B) -> coalesced 1536B chunk stores
    __syncthreads();
    ushort* xr = xh;
    #pragma unroll
    for (int mr=0; mr<MROW; mr++){
      int cob = (mbase+mr)*16 + q*4;
      #pragma unroll
      for (int nt=0; nt<8; nt++){
        int row = (nzh + (nt>>2))*64 + (nt&3)*16 + n;   // zi*64 + y8*8 + x8
        uint2 pk;
        pk.x = packbf2(fast_tanh(acc[mr][nt].x), fast_tanh(acc[mr][nt].y));
        pk.y = packbf2(fast_tanh(acc[mr][nt].z), fast_tanh(acc[mr][nt].w));
        *reinterpret_cast<uint2*>(&xr[row*96 + cob]) = pk;
      }
    }
    __syncthreads();
    ushort* dst = (ushort*)outp + (size_t)call*96*VV;
    const char* lb = reinterpret_cast<const char*>(xr);
    #pragma unroll
    for (int k=0; k<12; k++){
      int idx = tid + k*256;             // 3072 x uint4 = 48KB
      int chunk = idx/96;                // 32 chunks: (zi,y8)
      int off = idx - chunk*96;
      int zi = chunk>>3, y8 = chunk&7;
      size_t gb = (size_t)(((z0+zi)*HH + by + y8)*WW + bx)*192 + (size_t)off*16;
      *reinterpret_cast<uint4*>((char*)dst + gb) = *reinterpret_cast<const uint4*>(lb + idx*16);
    }
  }
}

// ---- sampling geometry (replicates the reference's channel->axis swap) ---
struct Geom { int x0,x1,y0,y1,z0,z1; float wx,wy,wz; };
__device__ __forceinline__ Geom make_geom(float zb, float yb, float xb,
                                          float o0, float o1, float o2){
  float g0 = clampf(zb + o0*(1.f/16.f), -1.f, 1.f);
  float g1 = clampf(yb + o1*(1.f/64.f), -1.f, 1.f);
  float g2 = clampf(xb + o2*(1.f/64.f), -1.f, 1.f);
  float ix = (g0+1.f)*0.5f*63.f;    // in [0,63]
  float iy = (g1+1.f)*0.5f*63.f;
  float iz = (g2+1.f)*0.5f*15.f;    // in [0,15]
  float fx=floorf(ix), fy=floorf(iy), fz=floorf(iz);
  Geom g;
  g.wx = ix-fx; g.wy = iy-fy; g.wz = iz-fz;
  g.x0 = (int)fx; g.x1 = imin(g.x0+1, WW-1);   // float clamp bounds x0 in [0,63]
  g.y0 = (int)fy; g.y1 = imin(g.y0+1, HH-1);
  g.z0 = (int)fz; g.z1 = imin(g.z0+1, DD-1);
  return g;
}

// ---- sample + attention + MFMA out conv + BN + relu ----------------------
// 4-lane cooperative slots; compact vols [head][y][x][z][32ch] (64B lines,
// L2-resident). Per (ky,kx) corner-pair: 2x b128 loads (z0,z1 lines),
// 8x v_perm_b32 to form (ch@z0,ch@z1) pairs, 8x v_dot2_f32_bf16 against
// packed (wyx*wz0, wyx*wz1). Roles 0/1 = K, 2/3 = V.
__global__ __launch_bounds__(256) void sample_attn_kernel(
    const ushort* __restrict__ qbuf, const ushort* __restrict__ offbuf,
    const uint* __restrict__ vols, const uint* __restrict__ woA,
    const float* __restrict__ outb, const float* __restrict__ bng,
    const float* __restrict__ bnb, const float* __restrict__ bnm,
    const float* __restrict__ bnv, float* __restrict__ dout)
{
  __shared__ ushort fsb[16*72];   // fused attn output, bf16 [vox16][64ci], 144B rows
  int t = threadIdx.x;
  int lane = t & 63;
  int m = __builtin_amdgcn_readfirstlane(t >> 6);   // head
  int slot = lane >> 2;
  int r = lane & 3;
  int bid = blockIdx.x;
  int xcd = bid & 7, islot = bid >> 3;
  int call = islot >> 9;
  int z = xcd*2 + ((islot >> 8) & 1);
  int rem = islot & 255;
  int y = rem >> 2;
  int x0 = (rem & 3) << 4;
  int x = x0 + slot;
  int vbase = (z*HH + y)*WW + x0;
  int v = vbase + slot;

  const ushort* qb = qbuf   + (size_t)call*CC*VV;
  const ushort* ob = offbuf + (size_t)call*96*VV;

  // q half: roles 0/2 -> ch m*16+0..7, roles 1/3 -> +8..15 (one 16B load)
  uint4 qu = *reinterpret_cast<const uint4*>(qb + (size_t)v*64 + m*16 + (r&1)*8);
  float qf[8];
  qf[0]=bflo(qu.x); qf[1]=bfhi(qu.x); qf[2]=bflo(qu.y); qf[3]=bfhi(qu.y);
  qf[4]=bflo(qu.z); qf[5]=bfhi(qu.z); qf[6]=bflo(qu.w); qf[7]=bfhi(qu.w);

  // all 24 offsets for head m at voxel v: 3 x 16B loads
  uint ou[12];
  {
    const uint4* op4 = reinterpret_cast<const uint4*>(ob + (size_t)v*96 + m*24);
    uint4 a = op4[0], b4 = op4[1], c4 = op4[2];
    ou[0]=a.x;  ou[1]=a.y;  ou[2]=a.z;  ou[3]=a.w;
    ou[4]=b4.x; ou[5]=b4.y; ou[6]=b4.z; ou[7]=b4.w;
    ou[8]=c4.x; ou[9]=c4.y; ou[10]=c4.z; ou[11]=c4.w;
  }

  float zbf = -1.f + (float)z*(2.f/15.f);
  float ybf = -1.f + (float)y*(2.f/63.f);
  float xbf = -1.f + (float)x*(2.f/63.f);

  const char* volb = reinterpret_cast<const char*>(vols) + (size_t)m*VV*64;
  float roleK = (r < 2) ? 1.f : 0.f;
  float lrun = 0.f;
  float fused[8];
  #pragma unroll
  for (int c=0;c<8;c++) fused[c]=0.f;

  #pragma unroll
  for (int s=0;s<NSAMP;s++){
    int i0 = 3*s, i1 = 3*s+1, i2 = 3*s+2;          // static after unroll
    float o0 = (i0&1) ? bfhi(ou[i0>>1]) : bflo(ou[i0>>1]);
    float o1 = (i1&1) ? bfhi(ou[i1>>1]) : bflo(ou[i1>>1]);
    float o2 = (i2&1) ? bfhi(ou[i2>>1]) : bflo(ou[i2>>1]);
    Geom g = make_geom(zbf,ybf,xbf,o0,o1,o2);
    int tz0 = g.z0*64 + r*16;
    int tz1 = g.z1*64 + r*16;
    float wx1 = g.wx, wx0 = 1.f-g.wx;
    float wy1 = g.wy, wy0 = 1.f-g.wy;
    float wz1 = g.wz, wz0 = 1.f-g.wz;
    float acc[8];
    #pragma unroll
    for (int c=0;c<8;c++) acc[c]=0.f;
    #pragma unroll
    for (int ky=0;ky<2;ky++)
    #pragma unroll
    for (int kx=0;kx<2;kx++){
      int cy = ky? g.y1:g.y0, cx = kx? g.x1:g.x0;
      float wyx = (ky? wy1:wy0)*(kx? wx1:wx0);
      float a0 = wyx*wz0, a1 = wyx*wz1;
      uint wzp;
      asm("v_cvt_pk_bf16_f32 %0, %1, %2" : "=v"(wzp) : "v"(a0), "v"(a1));
      int tb = ((cy<<6) + cx) << 10;
      const char* p = volb + tb;
      uint4 u0 = *reinterpret_cast<const uint4*>(p + tz0);
      uint4 u1 = *reinterpret_cast<const uint4*>(p + tz1);
      uint plo, phi;
      plo = __builtin_amdgcn_perm(u1.x, u0.x, 0x05040100u);
      phi = __builtin_amdgcn_perm(u1.x, u0.x, 0x07060302u);
      asm("v_dot2_f32_bf16 %0, %1, %2, %0" : "+v"(acc[0]) : "v"(plo), "v"(wzp));
      asm("v_dot2_f32_bf16 %0, %1, %2, %0" : "+v"(acc[1]) : "v"(phi), "v"(wzp));
      plo = __builtin_amdgcn_perm(u1.y, u0.y, 0x05040100u);
      phi = __builtin_amdgcn_perm(u1.y, u0.y, 0x07060302u);
      asm("v_dot2_f32_bf16 %0, %1, %2, %0" : "+v"(acc[2]) : "v"(plo), "v"(wzp));
      asm("v_dot2_f32_bf16 %0, %1, %2, %0" : "+v"(acc[3]) : "v"(phi), "v"(wzp));
      plo = __builtin_amdgcn_perm(u1.z, u0.z, 0x05040100u);
      phi = __builtin_amdgcn_perm(u1.z, u0.z, 0x07060302u);
      asm("v_dot2_f32_bf16 %0, %1, %2, %0" : "+v"(acc[4]) : "v"(plo), "v"(wzp));
      asm("v_dot2_f32_bf16 %0, %1, %2, %0" : "+v"(acc[5]) : "v"(phi), "v"(wzp));
      plo = __builtin_amdgcn_perm(u1.w, u0.w, 0x05040100u);
      phi = __builtin_amdgcn_perm(u1.w, u0.w, 0x07060302u);
      asm("v_dot2_f32_bf16 %0, %1, %2, %0" : "+v"(acc[6]) : "v"(plo), "v"(wzp));
      asm("v_dot2_f32_bf16 %0, %1, %2, %0" : "+v"(acc[7]) : "v"(phi), "v"(wzp));
    }
    float h = qf[0]*acc[0]+qf[1]*acc[1]+qf[2]*acc[2]+qf[3]*acc[3]
            + qf[4]*acc[4]+qf[5]*acc[5]+qf[6]*acc[6]+qf[7]*acc[7];
    h *= roleK;                 // roles 2/3 contribute 0
    h += __shfl_xor(h, 1);      // sum K halves within role pair
    h += __shfl_xor(h, 2);      // broadcast to V lanes
    float e = __expf(h);
    lrun += e;
    #pragma unroll
    for (int c=0;c<8;c++) fused[c] += e*acc[c];
  }
  float isum = 1.f/lrun;
  if (r >= 2){
    uint4 pk;
    pk.x = packbf2(fused[0]*isum, fused[1]*isum);
    pk.y = packbf2(fused[2]*isum, fused[3]*isum);
    pk.z = packbf2(fused[4]*isum, fused[5]*isum);
    pk.w = packbf2(fused[6]*isum, fused[7]*isum);
    *reinterpret_cast<uint4*>(&fsb[slot*72 + m*16 + (r&1)*8]) = pk;
  }
  __syncthreads();

  // out 1x1 conv via MFMA: wave m computes co-tile m (16 co) x 16 vox
  int qq = lane >> 4, n = lane & 15;
  f32x4 acco;
  acco.x=0.f; acco.y=0.f; acco.z=0.f; acco.w=0.f;
  const char* ldsb = reinterpret_cast<const char*>(fsb);
  const char* wac  = reinterpret_cast<const char*>(woA);
  #pragma unroll
  for (int ks=0; ks<2; ks++){
    bf16x8 af = *reinterpret_cast<const bf16x8*>(wac + (size_t)((ks*4 + m)*64 + lane)*16);
    bf16x8 bfv = *reinterpret_cast<const bf16x8*>(ldsb + (n*144 + qq*16 + ks*64));
    acco = __builtin_amdgcn_mfma_f32_16x16x32_bf16(af, bfv, acco, 0, 0, 0);
  }
  int choff = 64 + call*64;
  #pragma unroll
  for (int rr=0; rr<4; rr++){
    int co = m*16 + qq*4 + rr;
    float inv = rsqrtf(bnv[co] + 1e-5f) * bng[co];
    float val = (acco[rr] + outb[co] - bnm[co]) * inv + bnb[co];
    val = fmaxf(val, 0.f);
    dout[(size_t)(choff+co)*VV + vbase + n] = val;
  }
}

extern "C" void kernel_launch(void* const* d_in, const int* in_sizes, int n_in,
                              void* d_out, int out_size, void* d_ws, size_t ws_size,
                              hipStream_t stream){
  (void)in_sizes; (void)n_in; (void)out_size; (void)ws_size;
  const float* mid  = (const float*)d_in[0];
  const float* occ  = (const float*)d_in[1];
  const float* prev = (const float*)d_in[2];
  const float* off1w= (const float*)d_in[3];
  const float* off1b= (const float*)d_in[4];
  const float* off2w= (const float*)d_in[5];
  const float* kvw  = (const float*)d_in[6];
  const float* kvb  = (const float*)d_in[7];
  const float* qw   = (const float*)d_in[8];
  const float* qb   = (const float*)d_in[9];
  const float* outw = (const float*)d_in[10];
  const float* outb = (const float*)d_in[11];
  const float* bng  = (const float*)d_in[12];
  const float* bnb  = (const float*)d_in[13];
  const float* bnm  = (const float*)d_in[14];
  const float* bnv  = (const float*)d_in[15];
  float* out = (float*)d_out;

  uint*   vols  = (uint*)d_ws;                          // 4*VV*16 uints   (16.8 MB)
  ushort* qbuf  = (ushort*)(vols + (size_t)4*VV*16);    // 2*64*VV ushort  (16.8 MB)
  uint*   o1pk  = (uint*)(qbuf + (size_t)2*CC*VV);      // 2*32*VV uint    (16.8 MB)
  ushort* offb  = (ushort*)(o1pk + (size_t)2*32*VV);    // 2*96*VV ushort  (25.2 MB)
  uint*   wA1   = (uint*)(offb + (size_t)2*96*VV);      // 55296
  uint*   wA2   = wA1 + 55296;                          // 82944
  uint*   wo    = wA2 + 82944;                          // 2048
  uint*   wkv   = wo  + 2048;                           // 4096
  uint*   wq    = wkv + 4096;                           // 2048
  uint*   o0pk  = wq  + 2048;                           // 2*32*VV uint    (16.8 MB)

  prep<<<2620, 256, 0, stream>>>(occ, prev, o0pk, off1w, wA1, off2w, wA2,
                                 outw, wo, kvw, wkv, qw, wq);
  conv1_mfma<128,0><<<1024, 256, 0, stream>>>(mid, nullptr, wkv, kvb, (void*)vols, out);
  conv1_mfma<64,1><<<2048, 256, 0, stream>>>(nullptr, o0pk, wq, qb, (void*)qbuf, nullptr);
  conv3_mfma<64,1><<<512, 256, 0, stream>>>(o0pk, wA1, off1b, (void*)o1pk);
  conv3_mfma<96,0><<<512, 256, 0, stream>>>(o1pk, wA2, off1b, (void*)offb);
  sample_attn_kernel<<<8192, 256, 0, stream>>>(qbuf, offb, vols, wo,
      outb, bng, bnb, bnm, bnv, out);
}